// Round 1
// baseline (270.423 us; speedup 1.0000x reference)
//
#include <hip/hip_runtime.h>
#include <math.h>

#define B 256
#define V 128000
#define NOISE_MIN 1e-10f
#define CHUNKS 8                  // column chunks per row
#define BLOCK 256                 // 4 waves per block
#define VVEC (V / 4)              // 32000 float4 per row
#define CVEC (VVEC / CHUNKS)      // 4000 float4 per chunk

// first-occurrence argmax semantics: strictly greater wins; equal -> smaller index
__device__ __forceinline__ void upd(float v, int i, float& bv, int& bi) {
    if (v > bv || (v == bv && i < bi)) { bv = v; bi = i; }
}

// monotone float -> uint mapping; pack (value, ~idx) so u64 max == (bigger val, ties -> smaller idx)
__device__ __forceinline__ unsigned long long packKey(float v, int i) {
    unsigned int b = __float_as_uint(v);
    unsigned int u = (b & 0x80000000u) ? ~b : (b | 0x80000000u);
    return ((unsigned long long)u << 32) | (unsigned int)(~i);
}

__global__ __launch_bounds__(BLOCK, 8) void partial_kernel(
    const float* __restrict__ logits,
    const float* __restrict__ temps,
    const float* __restrict__ noise,
    unsigned long long* __restrict__ partials)
{
    const int row   = blockIdx.x / CHUNKS;
    const int chunk = blockIdx.x % CHUNKS;

    const float t = temps[row];
    const bool greedy = (t <= 0.0f);          // block-uniform branch
    const float invT = greedy ? 1.0f : (1.0f / t);

    const size_t base = (size_t)row * V;
    const float4* __restrict__ lg = reinterpret_cast<const float4*>(logits + base);
    const float4* __restrict__ nz = reinterpret_cast<const float4*>(noise + base);

    const int start = chunk * CVEC;
    const int end   = start + CVEC;

    // two independent accumulators -> breaks the serial compare chain, 2x loads in flight
    float bv0 = -INFINITY, bv1 = -INFINITY;
    int   bi0 = 0x7FFFFFFF, bi1 = 0x7FFFFFFF;

    int v = start + threadIdx.x;
    if (greedy) {
        // greedy rows: pure argmax of logits, skip noise traffic entirely
        for (; v + BLOCK < end; v += 2 * BLOCK) {
            float4 a = lg[v];
            float4 b = lg[v + BLOCK];
            int ia = v << 2, ib = (v + BLOCK) << 2;
            upd(a.x, ia + 0, bv0, bi0);
            upd(a.y, ia + 1, bv0, bi0);
            upd(a.z, ia + 2, bv0, bi0);
            upd(a.w, ia + 3, bv0, bi0);
            upd(b.x, ib + 0, bv1, bi1);
            upd(b.y, ib + 1, bv1, bi1);
            upd(b.z, ib + 2, bv1, bi1);
            upd(b.w, ib + 3, bv1, bi1);
        }
        if (v < end) {
            float4 a = lg[v];
            int ia = v << 2;
            upd(a.x, ia + 0, bv0, bi0);
            upd(a.y, ia + 1, bv0, bi0);
            upd(a.z, ia + 2, bv0, bi0);
            upd(a.w, ia + 3, bv0, bi0);
        }
    } else {
        // sampled rows: argmax( l/t - log(max(noise, 1e-10)) )
        for (; v + BLOCK < end; v += 2 * BLOCK) {
            float4 la = lg[v];
            float4 na = nz[v];
            float4 lb = lg[v + BLOCK];
            float4 nb = nz[v + BLOCK];
            int ia = v << 2, ib = (v + BLOCK) << 2;
            float kax = la.x * invT - __logf(fmaxf(na.x, NOISE_MIN));
            float kay = la.y * invT - __logf(fmaxf(na.y, NOISE_MIN));
            float kaz = la.z * invT - __logf(fmaxf(na.z, NOISE_MIN));
            float kaw = la.w * invT - __logf(fmaxf(na.w, NOISE_MIN));
            float kbx = lb.x * invT - __logf(fmaxf(nb.x, NOISE_MIN));
            float kby = lb.y * invT - __logf(fmaxf(nb.y, NOISE_MIN));
            float kbz = lb.z * invT - __logf(fmaxf(nb.z, NOISE_MIN));
            float kbw = lb.w * invT - __logf(fmaxf(nb.w, NOISE_MIN));
            upd(kax, ia + 0, bv0, bi0);
            upd(kay, ia + 1, bv0, bi0);
            upd(kaz, ia + 2, bv0, bi0);
            upd(kaw, ia + 3, bv0, bi0);
            upd(kbx, ib + 0, bv1, bi1);
            upd(kby, ib + 1, bv1, bi1);
            upd(kbz, ib + 2, bv1, bi1);
            upd(kbw, ib + 3, bv1, bi1);
        }
        if (v < end) {
            float4 la = lg[v];
            float4 na = nz[v];
            int ia = v << 2;
            float kax = la.x * invT - __logf(fmaxf(na.x, NOISE_MIN));
            float kay = la.y * invT - __logf(fmaxf(na.y, NOISE_MIN));
            float kaz = la.z * invT - __logf(fmaxf(na.z, NOISE_MIN));
            float kaw = la.w * invT - __logf(fmaxf(na.w, NOISE_MIN));
            upd(kax, ia + 0, bv0, bi0);
            upd(kay, ia + 1, bv0, bi0);
            upd(kaz, ia + 2, bv0, bi0);
            upd(kaw, ia + 3, bv0, bi0);
        }
    }

    // merge the two accumulators
    if (bv1 > bv0 || (bv1 == bv0 && bi1 < bi0)) { bv0 = bv1; bi0 = bi1; }

    // packed-key wave (64-lane) max reduction
    unsigned long long key = packKey(bv0, bi0);
    #pragma unroll
    for (int off = 32; off > 0; off >>= 1) {
        unsigned long long o = __shfl_down(key, off, 64);
        key = (o > key) ? o : key;
    }

    // cross-wave reduction (4 waves)
    __shared__ unsigned long long sKey[BLOCK / 64];
    const int wave = threadIdx.x >> 6;
    const int lane = threadIdx.x & 63;
    if (lane == 0) sKey[wave] = key;
    __syncthreads();

    if (threadIdx.x == 0) {
        unsigned long long k = sKey[0];
        #pragma unroll
        for (int w = 1; w < BLOCK / 64; ++w)
            k = (sKey[w] > k) ? sKey[w] : k;
        partials[blockIdx.x] = k;   // [row * CHUNKS + chunk]
    }
}

__global__ void reduce_kernel(const unsigned long long* __restrict__ partials,
                              int* __restrict__ out)
{
    const int row = blockIdx.x * blockDim.x + threadIdx.x;
    if (row < B) {
        unsigned long long k = partials[(size_t)row * CHUNKS];
        #pragma unroll
        for (int c = 1; c < CHUNKS; ++c) {
            unsigned long long o = partials[(size_t)row * CHUNKS + c];
            k = (o > k) ? o : k;
        }
        out[row] = (int)(~(unsigned int)k);   // decode index from low 32 bits
    }
}

extern "C" void kernel_launch(void* const* d_in, const int* in_sizes, int n_in,
                              void* d_out, int out_size, void* d_ws, size_t ws_size,
                              hipStream_t stream) {
    const float* logits = (const float*)d_in[0];   // [B, V] f32
    const float* temps  = (const float*)d_in[1];   // [B]    f32
    const float* noise  = (const float*)d_in[2];   // [B, V] f32
    int* out = (int*)d_out;                        // [B] int32 (jax int64 -> int32, x64 off)

    unsigned long long* partials = (unsigned long long*)d_ws;  // B*CHUNKS*8 = 16 KB

    partial_kernel<<<B * CHUNKS, BLOCK, 0, stream>>>(logits, temps, noise, partials);
    reduce_kernel<<<1, B, 0, stream>>>(partials, out);
}

// Round 2
// 268.950 us; speedup vs baseline: 1.0055x; 1.0055x over previous
//
#include <hip/hip_runtime.h>
#include <math.h>

#define B 256
#define V 128000
#define NOISE_MIN 1e-10f
#define CHUNKS 8                  // column chunks per row
#define BLOCK 256                 // 4 waves per block
#define VVEC (V / 4)              // 32000 float4 per row
#define CVEC (VVEC / CHUNKS)      // 4000 float4 per chunk
#define LOG2E 1.44269504088896340736f

// in-thread fast path: strictly greater wins. Each accumulator scans indices in
// increasing order, so '>' alone preserves first-occurrence (smallest index) on ties.
__device__ __forceinline__ void updf(float v, int i, float& bv, int& bi) {
    if (v > bv) { bv = v; bi = i; }
}
// full tie-break merge (used only at accumulator-merge time)
__device__ __forceinline__ void mergeAcc(float v, int i, float& bv, int& bi) {
    if (v > bv || (v == bv && i < bi)) { bv = v; bi = i; }
}

// monotone float -> uint mapping; pack (value, ~idx) so u64 max == (bigger val, ties -> smaller idx)
__device__ __forceinline__ unsigned long long packKey(float v, int i) {
    unsigned int b = __float_as_uint(v);
    unsigned int u = (b & 0x80000000u) ? ~b : (b | 0x80000000u);
    return ((unsigned long long)u << 32) | (unsigned int)(~i);
}

__device__ __forceinline__ float skey(float l, float n, float invT2) {
    // argmax(l/t - ln(noise)) == argmax(l*(invT*log2e) - log2(noise))  (positive scaling)
    return l * invT2 - __log2f(fmaxf(n, NOISE_MIN));
}

__global__ __launch_bounds__(BLOCK, 4) void partial_kernel(
    const float* __restrict__ logits,
    const float* __restrict__ temps,
    const float* __restrict__ noise,
    unsigned long long* __restrict__ partials)
{
    const int row   = blockIdx.x / CHUNKS;
    const int chunk = blockIdx.x % CHUNKS;

    const float t = temps[row];
    const bool greedy = (t <= 0.0f);          // block-uniform branch
    const float invT2 = (greedy ? 1.0f : (1.0f / t)) * LOG2E;

    const size_t base = (size_t)row * V;
    const float4* __restrict__ lg = reinterpret_cast<const float4*>(logits + base);
    const float4* __restrict__ nz = reinterpret_cast<const float4*>(noise + base);

    const int start = chunk * CVEC;
    const int end   = start + CVEC;

    // 4 independent accumulators -> 4 dependency chains, deep load batches
    float bv0 = -INFINITY, bv1 = -INFINITY, bv2 = -INFINITY, bv3 = -INFINITY;
    int   bi0 = 0x7FFFFFFF, bi1 = 0x7FFFFFFF, bi2 = 0x7FFFFFFF, bi3 = 0x7FFFFFFF;

    int v = start + threadIdx.x;

    if (greedy) {
        // greedy rows: pure argmax of logits, skip noise traffic entirely
        for (; v + 3 * BLOCK < end; v += 4 * BLOCK) {
            float4 a0 = lg[v];
            float4 a1 = lg[v + BLOCK];
            float4 a2 = lg[v + 2 * BLOCK];
            float4 a3 = lg[v + 3 * BLOCK];
            int i0 = v << 2, i1 = (v + BLOCK) << 2, i2 = (v + 2 * BLOCK) << 2, i3 = (v + 3 * BLOCK) << 2;
            updf(a0.x, i0 + 0, bv0, bi0); updf(a0.y, i0 + 1, bv0, bi0);
            updf(a0.z, i0 + 2, bv0, bi0); updf(a0.w, i0 + 3, bv0, bi0);
            updf(a1.x, i1 + 0, bv1, bi1); updf(a1.y, i1 + 1, bv1, bi1);
            updf(a1.z, i1 + 2, bv1, bi1); updf(a1.w, i1 + 3, bv1, bi1);
            updf(a2.x, i2 + 0, bv2, bi2); updf(a2.y, i2 + 1, bv2, bi2);
            updf(a2.z, i2 + 2, bv2, bi2); updf(a2.w, i2 + 3, bv2, bi2);
            updf(a3.x, i3 + 0, bv3, bi3); updf(a3.y, i3 + 1, bv3, bi3);
            updf(a3.z, i3 + 2, bv3, bi3); updf(a3.w, i3 + 3, bv3, bi3);
        }
        for (; v < end; v += BLOCK) {
            float4 a0 = lg[v];
            int i0 = v << 2;
            updf(a0.x, i0 + 0, bv0, bi0); updf(a0.y, i0 + 1, bv0, bi0);
            updf(a0.z, i0 + 2, bv0, bi0); updf(a0.w, i0 + 3, bv0, bi0);
        }
    } else {
        // sampled rows: argmax( l/t - log(max(noise, 1e-10)) ), log2-domain
        for (; v + 3 * BLOCK < end; v += 4 * BLOCK) {
            float4 l0 = lg[v];             float4 n0 = nz[v];
            float4 l1 = lg[v + BLOCK];     float4 n1 = nz[v + BLOCK];
            float4 l2 = lg[v + 2 * BLOCK]; float4 n2 = nz[v + 2 * BLOCK];
            float4 l3 = lg[v + 3 * BLOCK]; float4 n3 = nz[v + 3 * BLOCK];
            int i0 = v << 2, i1 = (v + BLOCK) << 2, i2 = (v + 2 * BLOCK) << 2, i3 = (v + 3 * BLOCK) << 2;
            updf(skey(l0.x, n0.x, invT2), i0 + 0, bv0, bi0);
            updf(skey(l0.y, n0.y, invT2), i0 + 1, bv0, bi0);
            updf(skey(l0.z, n0.z, invT2), i0 + 2, bv0, bi0);
            updf(skey(l0.w, n0.w, invT2), i0 + 3, bv0, bi0);
            updf(skey(l1.x, n1.x, invT2), i1 + 0, bv1, bi1);
            updf(skey(l1.y, n1.y, invT2), i1 + 1, bv1, bi1);
            updf(skey(l1.z, n1.z, invT2), i1 + 2, bv1, bi1);
            updf(skey(l1.w, n1.w, invT2), i1 + 3, bv1, bi1);
            updf(skey(l2.x, n2.x, invT2), i2 + 0, bv2, bi2);
            updf(skey(l2.y, n2.y, invT2), i2 + 1, bv2, bi2);
            updf(skey(l2.z, n2.z, invT2), i2 + 2, bv2, bi2);
            updf(skey(l2.w, n2.w, invT2), i2 + 3, bv2, bi2);
            updf(skey(l3.x, n3.x, invT2), i3 + 0, bv3, bi3);
            updf(skey(l3.y, n3.y, invT2), i3 + 1, bv3, bi3);
            updf(skey(l3.z, n3.z, invT2), i3 + 2, bv3, bi3);
            updf(skey(l3.w, n3.w, invT2), i3 + 3, bv3, bi3);
        }
        for (; v < end; v += BLOCK) {
            float4 l0 = lg[v];
            float4 n0 = nz[v];
            int i0 = v << 2;
            updf(skey(l0.x, n0.x, invT2), i0 + 0, bv0, bi0);
            updf(skey(l0.y, n0.y, invT2), i0 + 1, bv0, bi0);
            updf(skey(l0.z, n0.z, invT2), i0 + 2, bv0, bi0);
            updf(skey(l0.w, n0.w, invT2), i0 + 3, bv0, bi0);
        }
    }

    // merge the 4 accumulators with full tie-break (cross-chain ties need index compare)
    mergeAcc(bv1, bi1, bv0, bi0);
    mergeAcc(bv2, bi2, bv0, bi0);
    mergeAcc(bv3, bi3, bv0, bi0);

    // packed-key wave (64-lane) max reduction
    unsigned long long key = packKey(bv0, bi0);
    #pragma unroll
    for (int off = 32; off > 0; off >>= 1) {
        unsigned long long o = __shfl_down(key, off, 64);
        key = (o > key) ? o : key;
    }

    // cross-wave reduction (4 waves)
    __shared__ unsigned long long sKey[BLOCK / 64];
    const int wave = threadIdx.x >> 6;
    const int lane = threadIdx.x & 63;
    if (lane == 0) sKey[wave] = key;
    __syncthreads();

    if (threadIdx.x == 0) {
        unsigned long long k = sKey[0];
        #pragma unroll
        for (int w = 1; w < BLOCK / 64; ++w)
            k = (sKey[w] > k) ? sKey[w] : k;
        partials[blockIdx.x] = k;   // [row * CHUNKS + chunk]
    }
}

__global__ void reduce_kernel(const unsigned long long* __restrict__ partials,
                              int* __restrict__ out)
{
    const int row = blockIdx.x * blockDim.x + threadIdx.x;
    if (row < B) {
        unsigned long long k = partials[(size_t)row * CHUNKS];
        #pragma unroll
        for (int c = 1; c < CHUNKS; ++c) {
            unsigned long long o = partials[(size_t)row * CHUNKS + c];
            k = (o > k) ? o : k;
        }
        out[row] = (int)(~(unsigned int)k);   // decode index from low 32 bits
    }
}

extern "C" void kernel_launch(void* const* d_in, const int* in_sizes, int n_in,
                              void* d_out, int out_size, void* d_ws, size_t ws_size,
                              hipStream_t stream) {
    const float* logits = (const float*)d_in[0];   // [B, V] f32
    const float* temps  = (const float*)d_in[1];   // [B]    f32
    const float* noise  = (const float*)d_in[2];   // [B, V] f32
    int* out = (int*)d_out;                        // [B] int32 (jax int64 -> int32, x64 off)

    unsigned long long* partials = (unsigned long long*)d_ws;  // B*CHUNKS*8 = 16 KB

    partial_kernel<<<B * CHUNKS, BLOCK, 0, stream>>>(logits, temps, noise, partials);
    reduce_kernel<<<1, B, 0, stream>>>(partials, out);
}

// Round 3
// 267.040 us; speedup vs baseline: 1.0127x; 1.0072x over previous
//
#include <hip/hip_runtime.h>
#include <math.h>

#define B 256
#define V 128000
#define NOISE_MIN 1e-10f
#define CHUNKS 8                  // column chunks per row
#define BLOCK 256                 // 4 waves per block
#define VVEC (V / 4)              // 32000 float4 per row
#define CVEC (VVEC / CHUNKS)      // 4000 float4 per chunk
#define STRIDE (2 * BLOCK)        // 512 float4 per pipeline iter (2 per thread per stream)
#define NFULL (CVEC / STRIDE)     // 7 full pipeline iterations; tail = 416 float4
#define LOG2E 1.44269504088896340736f

// in-thread fast path: strictly greater wins. Each accumulator scans indices in
// increasing order, so '>' alone preserves first-occurrence (smallest index) on ties.
__device__ __forceinline__ void updf(float v, int i, float& bv, int& bi) {
    if (v > bv) { bv = v; bi = i; }
}
// full tie-break merge (used only at accumulator-merge time)
__device__ __forceinline__ void mergeAcc(float v, int i, float& bv, int& bi) {
    if (v > bv || (v == bv && i < bi)) { bv = v; bi = i; }
}

// monotone float -> uint mapping; pack (value, ~idx) so u64 max == (bigger val, ties -> smaller idx)
__device__ __forceinline__ unsigned long long packKey(float v, int i) {
    unsigned int b = __float_as_uint(v);
    unsigned int u = (b & 0x80000000u) ? ~b : (b | 0x80000000u);
    return ((unsigned long long)u << 32) | (unsigned int)(~i);
}

__device__ __forceinline__ float skey(float l, float n, float invT2) {
    // argmax(l/t - ln(noise)) == argmax(l*(invT*log2e) - log2(noise))  (positive scaling)
    return l * invT2 - __log2f(fmaxf(n, NOISE_MIN));
}

__global__ __launch_bounds__(BLOCK, 4) void partial_kernel(
    const float* __restrict__ logits,
    const float* __restrict__ temps,
    const float* __restrict__ noise,
    unsigned long long* __restrict__ partials)
{
    const int row   = blockIdx.x / CHUNKS;
    const int chunk = blockIdx.x % CHUNKS;

    const float t = temps[row];
    const bool greedy = (t <= 0.0f);          // block-uniform branch
    const float invT2 = (greedy ? 1.0f : (1.0f / t)) * LOG2E;

    const size_t base = (size_t)row * V;
    const float4* __restrict__ lg = reinterpret_cast<const float4*>(logits + base);
    const float4* __restrict__ nz = reinterpret_cast<const float4*>(noise + base);

    const int start = chunk * CVEC;
    const int end   = start + CVEC;

    // 4 independent accumulators -> 4 compare chains; each sees increasing indices
    float bv0 = -INFINITY, bv1 = -INFINITY, bv2 = -INFINITY, bv3 = -INFINITY;
    int   bi0 = 0x7FFFFFFF, bi1 = 0x7FFFFFFF, bi2 = 0x7FFFFFFF, bi3 = 0x7FFFFFFF;

    if (greedy) {
        // greedy rows: pure argmax of logits, skip noise traffic entirely.
        // explicit 2-stage prefetch pipeline: loads for iter k+1 in flight during consume of iter k
        int v = start + threadIdx.x;
        float4 pl0 = lg[v];
        float4 pl1 = lg[v + BLOCK];
        #pragma unroll 2
        for (int k = 1; k < NFULL; ++k) {
            const int vn = start + k * STRIDE + threadIdx.x;
            float4 cl0 = pl0, cl1 = pl1;
            pl0 = lg[vn];                 // prefetch next iter
            pl1 = lg[vn + BLOCK];
            int i0 = v << 2, i1 = (v + BLOCK) << 2;
            updf(cl0.x, i0 + 0, bv0, bi0); updf(cl0.y, i0 + 1, bv0, bi0);
            updf(cl0.z, i0 + 2, bv1, bi1); updf(cl0.w, i0 + 3, bv1, bi1);
            updf(cl1.x, i1 + 0, bv2, bi2); updf(cl1.y, i1 + 1, bv2, bi2);
            updf(cl1.z, i1 + 2, bv3, bi3); updf(cl1.w, i1 + 3, bv3, bi3);
            v = vn;
        }
        { // drain
            int i0 = v << 2, i1 = (v + BLOCK) << 2;
            updf(pl0.x, i0 + 0, bv0, bi0); updf(pl0.y, i0 + 1, bv0, bi0);
            updf(pl0.z, i0 + 2, bv1, bi1); updf(pl0.w, i0 + 3, bv1, bi1);
            updf(pl1.x, i1 + 0, bv2, bi2); updf(pl1.y, i1 + 1, bv2, bi2);
            updf(pl1.z, i1 + 2, bv3, bi3); updf(pl1.w, i1 + 3, bv3, bi3);
        }
        // tail: 416 float4 (guarded)
        for (int w = start + NFULL * STRIDE + threadIdx.x; w < end; w += BLOCK) {
            float4 a = lg[w];
            int i0 = w << 2;
            updf(a.x, i0 + 0, bv0, bi0); updf(a.y, i0 + 1, bv0, bi0);
            updf(a.z, i0 + 2, bv1, bi1); updf(a.w, i0 + 3, bv1, bi1);
        }
    } else {
        // sampled rows: argmax( l*(invT*log2e) - log2(max(noise, 1e-10)) )
        int v = start + threadIdx.x;
        float4 pl0 = lg[v];
        float4 pl1 = lg[v + BLOCK];
        float4 pn0 = nz[v];
        float4 pn1 = nz[v + BLOCK];
        #pragma unroll 2
        for (int k = 1; k < NFULL; ++k) {
            const int vn = start + k * STRIDE + threadIdx.x;
            float4 cl0 = pl0, cl1 = pl1, cn0 = pn0, cn1 = pn1;
            pl0 = lg[vn];                 // prefetch next iter: 4 dwordx4 in flight
            pl1 = lg[vn + BLOCK];
            pn0 = nz[vn];
            pn1 = nz[vn + BLOCK];
            int i0 = v << 2, i1 = (v + BLOCK) << 2;
            updf(skey(cl0.x, cn0.x, invT2), i0 + 0, bv0, bi0);
            updf(skey(cl0.y, cn0.y, invT2), i0 + 1, bv0, bi0);
            updf(skey(cl0.z, cn0.z, invT2), i0 + 2, bv1, bi1);
            updf(skey(cl0.w, cn0.w, invT2), i0 + 3, bv1, bi1);
            updf(skey(cl1.x, cn1.x, invT2), i1 + 0, bv2, bi2);
            updf(skey(cl1.y, cn1.y, invT2), i1 + 1, bv2, bi2);
            updf(skey(cl1.z, cn1.z, invT2), i1 + 2, bv3, bi3);
            updf(skey(cl1.w, cn1.w, invT2), i1 + 3, bv3, bi3);
            v = vn;
        }
        { // drain
            int i0 = v << 2, i1 = (v + BLOCK) << 2;
            updf(skey(pl0.x, pn0.x, invT2), i0 + 0, bv0, bi0);
            updf(skey(pl0.y, pn0.y, invT2), i0 + 1, bv0, bi0);
            updf(skey(pl0.z, pn0.z, invT2), i0 + 2, bv1, bi1);
            updf(skey(pl0.w, pn0.w, invT2), i0 + 3, bv1, bi1);
            updf(skey(pl1.x, pn1.x, invT2), i1 + 0, bv2, bi2);
            updf(skey(pl1.y, pn1.y, invT2), i1 + 1, bv2, bi2);
            updf(skey(pl1.z, pn1.z, invT2), i1 + 2, bv3, bi3);
            updf(skey(pl1.w, pn1.w, invT2), i1 + 3, bv3, bi3);
        }
        // tail: 416 float4 (guarded)
        for (int w = start + NFULL * STRIDE + threadIdx.x; w < end; w += BLOCK) {
            float4 l = lg[w];
            float4 n = nz[w];
            int i0 = w << 2;
            updf(skey(l.x, n.x, invT2), i0 + 0, bv0, bi0);
            updf(skey(l.y, n.y, invT2), i0 + 1, bv0, bi0);
            updf(skey(l.z, n.z, invT2), i0 + 2, bv1, bi1);
            updf(skey(l.w, n.w, invT2), i0 + 3, bv1, bi1);
        }
    }

    // merge the 4 accumulators with full tie-break (cross-chain ties need index compare)
    mergeAcc(bv1, bi1, bv0, bi0);
    mergeAcc(bv2, bi2, bv0, bi0);
    mergeAcc(bv3, bi3, bv0, bi0);

    // packed-key wave (64-lane) max reduction
    unsigned long long key = packKey(bv0, bi0);
    #pragma unroll
    for (int off = 32; off > 0; off >>= 1) {
        unsigned long long o = __shfl_down(key, off, 64);
        key = (o > key) ? o : key;
    }

    // cross-wave reduction (4 waves)
    __shared__ unsigned long long sKey[BLOCK / 64];
    const int wave = threadIdx.x >> 6;
    const int lane = threadIdx.x & 63;
    if (lane == 0) sKey[wave] = key;
    __syncthreads();

    if (threadIdx.x == 0) {
        unsigned long long k = sKey[0];
        #pragma unroll
        for (int w = 1; w < BLOCK / 64; ++w)
            k = (sKey[w] > k) ? sKey[w] : k;
        partials[blockIdx.x] = k;   // [row * CHUNKS + chunk]
    }
}

__global__ void reduce_kernel(const unsigned long long* __restrict__ partials,
                              int* __restrict__ out)
{
    const int row = blockIdx.x * blockDim.x + threadIdx.x;
    if (row < B) {
        unsigned long long k = partials[(size_t)row * CHUNKS];
        #pragma unroll
        for (int c = 1; c < CHUNKS; ++c) {
            unsigned long long o = partials[(size_t)row * CHUNKS + c];
            k = (o > k) ? o : k;
        }
        out[row] = (int)(~(unsigned int)k);   // decode index from low 32 bits
    }
}

extern "C" void kernel_launch(void* const* d_in, const int* in_sizes, int n_in,
                              void* d_out, int out_size, void* d_ws, size_t ws_size,
                              hipStream_t stream) {
    const float* logits = (const float*)d_in[0];   // [B, V] f32
    const float* temps  = (const float*)d_in[1];   // [B]    f32
    const float* noise  = (const float*)d_in[2];   // [B, V] f32
    int* out = (int*)d_out;                        // [B] int32 (jax int64 -> int32, x64 off)

    unsigned long long* partials = (unsigned long long*)d_ws;  // B*CHUNKS*8 = 16 KB

    partial_kernel<<<B * CHUNKS, BLOCK, 0, stream>>>(logits, temps, noise, partials);
    reduce_kernel<<<1, B, 0, stream>>>(partials, out);
}

// Round 4
// 243.198 us; speedup vs baseline: 1.1119x; 1.0980x over previous
//
#include <hip/hip_runtime.h>
#include <math.h>

#define B 256
#define V 128000
#define NOISE_MIN 1e-10f
#define CHUNKS 8                  // column chunks per row
#define BLOCK 256                 // 4 waves per block
#define VVEC (V / 4)              // 32000 float4 per row
#define CVEC (VVEC / CHUNKS)      // 4000 float4 per chunk
#define STRIDE (2 * BLOCK)        // 512 float4 per pipeline iter (2 per thread per stream)
#define NFULL (CVEC / STRIDE)     // 7 full pipeline iterations; tail = 416 float4
#define LOG2E 1.44269504088896340736f

// native clang vector type so __builtin_nontemporal_load works on 16B loads
typedef float f32x4 __attribute__((ext_vector_type(4)));

__device__ __forceinline__ f32x4 ntload(const f32x4* __restrict__ p) {
    // nontemporal: bypass cache allocation on the streaming read path (emits global_load ... nt)
    return __builtin_nontemporal_load(p);
}

// in-thread fast path: strictly greater wins. Each accumulator scans indices in
// increasing order, so '>' alone preserves first-occurrence (smallest index) on ties.
__device__ __forceinline__ void updf(float v, int i, float& bv, int& bi) {
    if (v > bv) { bv = v; bi = i; }
}
// full tie-break merge (used only at accumulator-merge time)
__device__ __forceinline__ void mergeAcc(float v, int i, float& bv, int& bi) {
    if (v > bv || (v == bv && i < bi)) { bv = v; bi = i; }
}

// monotone float -> uint mapping; pack (value, ~idx) so u64 max == (bigger val, ties -> smaller idx)
__device__ __forceinline__ unsigned long long packKey(float v, int i) {
    unsigned int b = __float_as_uint(v);
    unsigned int u = (b & 0x80000000u) ? ~b : (b | 0x80000000u);
    return ((unsigned long long)u << 32) | (unsigned int)(~i);
}

__device__ __forceinline__ float skey(float l, float n, float invT2) {
    // argmax(l/t - ln(noise)) == argmax(l*(invT*log2e) - log2(noise))  (positive scaling)
    return l * invT2 - __log2f(fmaxf(n, NOISE_MIN));
}

__global__ __launch_bounds__(BLOCK, 4) void partial_kernel(
    const float* __restrict__ logits,
    const float* __restrict__ temps,
    const float* __restrict__ noise,
    unsigned long long* __restrict__ partials)
{
    const int row   = blockIdx.x / CHUNKS;
    const int chunk = blockIdx.x % CHUNKS;

    const float t = temps[row];
    const bool greedy = (t <= 0.0f);          // block-uniform branch
    const float invT2 = (greedy ? 1.0f : (1.0f / t)) * LOG2E;

    const size_t base = (size_t)row * V;
    const f32x4* __restrict__ lg = reinterpret_cast<const f32x4*>(logits + base);
    const f32x4* __restrict__ nz = reinterpret_cast<const f32x4*>(noise + base);

    const int start = chunk * CVEC;
    const int end   = start + CVEC;

    // 4 independent accumulators -> 4 compare chains; each sees increasing indices
    float bv0 = -INFINITY, bv1 = -INFINITY, bv2 = -INFINITY, bv3 = -INFINITY;
    int   bi0 = 0x7FFFFFFF, bi1 = 0x7FFFFFFF, bi2 = 0x7FFFFFFF, bi3 = 0x7FFFFFFF;

    if (greedy) {
        // greedy rows: pure argmax of logits, skip noise traffic entirely.
        // explicit 2-stage prefetch pipeline: loads for iter k+1 in flight during consume of iter k
        int v = start + threadIdx.x;
        f32x4 pl0 = ntload(lg + v);
        f32x4 pl1 = ntload(lg + v + BLOCK);
        #pragma unroll 2
        for (int k = 1; k < NFULL; ++k) {
            const int vn = start + k * STRIDE + threadIdx.x;
            f32x4 cl0 = pl0, cl1 = pl1;
            pl0 = ntload(lg + vn);                 // prefetch next iter
            pl1 = ntload(lg + vn + BLOCK);
            int i0 = v << 2, i1 = (v + BLOCK) << 2;
            updf(cl0.x, i0 + 0, bv0, bi0); updf(cl0.y, i0 + 1, bv0, bi0);
            updf(cl0.z, i0 + 2, bv1, bi1); updf(cl0.w, i0 + 3, bv1, bi1);
            updf(cl1.x, i1 + 0, bv2, bi2); updf(cl1.y, i1 + 1, bv2, bi2);
            updf(cl1.z, i1 + 2, bv3, bi3); updf(cl1.w, i1 + 3, bv3, bi3);
            v = vn;
        }
        { // drain
            int i0 = v << 2, i1 = (v + BLOCK) << 2;
            updf(pl0.x, i0 + 0, bv0, bi0); updf(pl0.y, i0 + 1, bv0, bi0);
            updf(pl0.z, i0 + 2, bv1, bi1); updf(pl0.w, i0 + 3, bv1, bi1);
            updf(pl1.x, i1 + 0, bv2, bi2); updf(pl1.y, i1 + 1, bv2, bi2);
            updf(pl1.z, i1 + 2, bv3, bi3); updf(pl1.w, i1 + 3, bv3, bi3);
        }
        // tail: 416 float4 (guarded)
        for (int w = start + NFULL * STRIDE + threadIdx.x; w < end; w += BLOCK) {
            f32x4 a = ntload(lg + w);
            int i0 = w << 2;
            updf(a.x, i0 + 0, bv0, bi0); updf(a.y, i0 + 1, bv0, bi0);
            updf(a.z, i0 + 2, bv1, bi1); updf(a.w, i0 + 3, bv1, bi1);
        }
    } else {
        // sampled rows: argmax( l*(invT*log2e) - log2(max(noise, 1e-10)) )
        int v = start + threadIdx.x;
        f32x4 pl0 = ntload(lg + v);
        f32x4 pl1 = ntload(lg + v + BLOCK);
        f32x4 pn0 = ntload(nz + v);
        f32x4 pn1 = ntload(nz + v + BLOCK);
        #pragma unroll 2
        for (int k = 1; k < NFULL; ++k) {
            const int vn = start + k * STRIDE + threadIdx.x;
            f32x4 cl0 = pl0, cl1 = pl1, cn0 = pn0, cn1 = pn1;
            pl0 = ntload(lg + vn);                 // prefetch next iter: 4 dwordx4 in flight
            pl1 = ntload(lg + vn + BLOCK);
            pn0 = ntload(nz + vn);
            pn1 = ntload(nz + vn + BLOCK);
            int i0 = v << 2, i1 = (v + BLOCK) << 2;
            updf(skey(cl0.x, cn0.x, invT2), i0 + 0, bv0, bi0);
            updf(skey(cl0.y, cn0.y, invT2), i0 + 1, bv0, bi0);
            updf(skey(cl0.z, cn0.z, invT2), i0 + 2, bv1, bi1);
            updf(skey(cl0.w, cn0.w, invT2), i0 + 3, bv1, bi1);
            updf(skey(cl1.x, cn1.x, invT2), i1 + 0, bv2, bi2);
            updf(skey(cl1.y, cn1.y, invT2), i1 + 1, bv2, bi2);
            updf(skey(cl1.z, cn1.z, invT2), i1 + 2, bv3, bi3);
            updf(skey(cl1.w, cn1.w, invT2), i1 + 3, bv3, bi3);
            v = vn;
        }
        { // drain
            int i0 = v << 2, i1 = (v + BLOCK) << 2;
            updf(skey(pl0.x, pn0.x, invT2), i0 + 0, bv0, bi0);
            updf(skey(pl0.y, pn0.y, invT2), i0 + 1, bv0, bi0);
            updf(skey(pl0.z, pn0.z, invT2), i0 + 2, bv1, bi1);
            updf(skey(pl0.w, pn0.w, invT2), i0 + 3, bv1, bi1);
            updf(skey(pl1.x, pn1.x, invT2), i1 + 0, bv2, bi2);
            updf(skey(pl1.y, pn1.y, invT2), i1 + 1, bv2, bi2);
            updf(skey(pl1.z, pn1.z, invT2), i1 + 2, bv3, bi3);
            updf(skey(pl1.w, pn1.w, invT2), i1 + 3, bv3, bi3);
        }
        // tail: 416 float4 (guarded)
        for (int w = start + NFULL * STRIDE + threadIdx.x; w < end; w += BLOCK) {
            f32x4 l = ntload(lg + w);
            f32x4 n = ntload(nz + w);
            int i0 = w << 2;
            updf(skey(l.x, n.x, invT2), i0 + 0, bv0, bi0);
            updf(skey(l.y, n.y, invT2), i0 + 1, bv0, bi0);
            updf(skey(l.z, n.z, invT2), i0 + 2, bv1, bi1);
            updf(skey(l.w, n.w, invT2), i0 + 3, bv1, bi1);
        }
    }

    // merge the 4 accumulators with full tie-break (cross-chain ties need index compare)
    mergeAcc(bv1, bi1, bv0, bi0);
    mergeAcc(bv2, bi2, bv0, bi0);
    mergeAcc(bv3, bi3, bv0, bi0);

    // packed-key wave (64-lane) max reduction
    unsigned long long key = packKey(bv0, bi0);
    #pragma unroll
    for (int off = 32; off > 0; off >>= 1) {
        unsigned long long o = __shfl_down(key, off, 64);
        key = (o > key) ? o : key;
    }

    // cross-wave reduction (4 waves)
    __shared__ unsigned long long sKey[BLOCK / 64];
    const int wave = threadIdx.x >> 6;
    const int lane = threadIdx.x & 63;
    if (lane == 0) sKey[wave] = key;
    __syncthreads();

    if (threadIdx.x == 0) {
        unsigned long long k = sKey[0];
        #pragma unroll
        for (int w = 1; w < BLOCK / 64; ++w)
            k = (sKey[w] > k) ? sKey[w] : k;
        partials[blockIdx.x] = k;   // [row * CHUNKS + chunk]
    }
}

__global__ void reduce_kernel(const unsigned long long* __restrict__ partials,
                              int* __restrict__ out)
{
    const int row = blockIdx.x * blockDim.x + threadIdx.x;
    if (row < B) {
        unsigned long long k = partials[(size_t)row * CHUNKS];
        #pragma unroll
        for (int c = 1; c < CHUNKS; ++c) {
            unsigned long long o = partials[(size_t)row * CHUNKS + c];
            k = (o > k) ? o : k;
        }
        out[row] = (int)(~(unsigned int)k);   // decode index from low 32 bits
    }
}

extern "C" void kernel_launch(void* const* d_in, const int* in_sizes, int n_in,
                              void* d_out, int out_size, void* d_ws, size_t ws_size,
                              hipStream_t stream) {
    const float* logits = (const float*)d_in[0];   // [B, V] f32
    const float* temps  = (const float*)d_in[1];   // [B]    f32
    const float* noise  = (const float*)d_in[2];   // [B, V] f32
    int* out = (int*)d_out;                        // [B] int32 (jax int64 -> int32, x64 off)

    unsigned long long* partials = (unsigned long long*)d_ws;  // B*CHUNKS*8 = 16 KB

    partial_kernel<<<B * CHUNKS, BLOCK, 0, stream>>>(logits, temps, noise, partials);
    reduce_kernel<<<1, B, 0, stream>>>(partials, out);
}

// Round 5
// 242.451 us; speedup vs baseline: 1.1154x; 1.0031x over previous
//
#include <hip/hip_runtime.h>
#include <math.h>

#define B 256
#define V 128000
#define NOISE_MIN 1e-10f
#define CHUNKS 8                  // column chunks per row
#define BLOCK 256                 // 4 waves per block
#define VVEC (V / 4)              // 32000 float4 per row
#define CVEC (VVEC / CHUNKS)      // 4000 float4 per chunk
#define STRIDE (2 * BLOCK)        // 512 float4 per pipeline iter (2 per thread per stream)
#define NFULL (CVEC / STRIDE)     // 7 full pipeline iterations; tail = 416 float4
#define LOG2E 1.44269504088896340736f

// native clang vector type so __builtin_nontemporal_load works on 16B loads
typedef float f32x4 __attribute__((ext_vector_type(4)));

__device__ __forceinline__ f32x4 ntload(const f32x4* __restrict__ p) {
    // nontemporal: bypass cache allocation on the streaming read path (emits global_load ... nt)
    return __builtin_nontemporal_load(p);
}

// in-thread fast path: strictly greater wins. Each accumulator scans indices in
// increasing order, so '>' alone preserves first-occurrence (smallest index) on ties.
__device__ __forceinline__ void updf(float v, int i, float& bv, int& bi) {
    if (v > bv) { bv = v; bi = i; }
}
// full tie-break merge (used only at accumulator-merge time)
__device__ __forceinline__ void mergeAcc(float v, int i, float& bv, int& bi) {
    if (v > bv || (v == bv && i < bi)) { bv = v; bi = i; }
}

// monotone float -> uint mapping; pack (value, ~idx) so u64 max == (bigger val, ties -> smaller idx)
__device__ __forceinline__ unsigned long long packKey(float v, int i) {
    unsigned int b = __float_as_uint(v);
    unsigned int u = (b & 0x80000000u) ? ~b : (b | 0x80000000u);
    return ((unsigned long long)u << 32) | (unsigned int)(~i);
}

__device__ __forceinline__ float skey(float l, float n, float invT2) {
    // argmax(l/t - ln(noise)) == argmax(l*(invT*log2e) - log2(noise))  (positive scaling)
    return l * invT2 - __log2f(fmaxf(n, NOISE_MIN));
}

// 8 blocks/CU (32 waves/CU): all 2048 blocks co-resident; doubles time-averaged
// outstanding NT-read requests per CU vs the (256,4) config. VGPR=40 fits the 64 cap.
__global__ __launch_bounds__(BLOCK, 8) void partial_kernel(
    const float* __restrict__ logits,
    const float* __restrict__ temps,
    const float* __restrict__ noise,
    unsigned long long* __restrict__ partials)
{
    const int row   = blockIdx.x / CHUNKS;
    const int chunk = blockIdx.x % CHUNKS;

    const float t = temps[row];
    const bool greedy = (t <= 0.0f);          // block-uniform branch
    const float invT2 = (greedy ? 1.0f : (1.0f / t)) * LOG2E;

    const size_t base = (size_t)row * V;
    const f32x4* __restrict__ lg = reinterpret_cast<const f32x4*>(logits + base);
    const f32x4* __restrict__ nz = reinterpret_cast<const f32x4*>(noise + base);

    const int start = chunk * CVEC;
    const int end   = start + CVEC;

    // 4 independent accumulators -> 4 compare chains; each sees increasing indices
    float bv0 = -INFINITY, bv1 = -INFINITY, bv2 = -INFINITY, bv3 = -INFINITY;
    int   bi0 = 0x7FFFFFFF, bi1 = 0x7FFFFFFF, bi2 = 0x7FFFFFFF, bi3 = 0x7FFFFFFF;

    if (greedy) {
        // greedy rows: pure argmax of logits, skip noise traffic entirely.
        // explicit 2-stage prefetch pipeline: loads for iter k+1 in flight during consume of iter k
        int v = start + threadIdx.x;
        f32x4 pl0 = ntload(lg + v);
        f32x4 pl1 = ntload(lg + v + BLOCK);
        #pragma unroll 2
        for (int k = 1; k < NFULL; ++k) {
            const int vn = start + k * STRIDE + threadIdx.x;
            f32x4 cl0 = pl0, cl1 = pl1;
            pl0 = ntload(lg + vn);                 // prefetch next iter
            pl1 = ntload(lg + vn + BLOCK);
            int i0 = v << 2, i1 = (v + BLOCK) << 2;
            updf(cl0.x, i0 + 0, bv0, bi0); updf(cl0.y, i0 + 1, bv0, bi0);
            updf(cl0.z, i0 + 2, bv1, bi1); updf(cl0.w, i0 + 3, bv1, bi1);
            updf(cl1.x, i1 + 0, bv2, bi2); updf(cl1.y, i1 + 1, bv2, bi2);
            updf(cl1.z, i1 + 2, bv3, bi3); updf(cl1.w, i1 + 3, bv3, bi3);
            v = vn;
        }
        { // drain
            int i0 = v << 2, i1 = (v + BLOCK) << 2;
            updf(pl0.x, i0 + 0, bv0, bi0); updf(pl0.y, i0 + 1, bv0, bi0);
            updf(pl0.z, i0 + 2, bv1, bi1); updf(pl0.w, i0 + 3, bv1, bi1);
            updf(pl1.x, i1 + 0, bv2, bi2); updf(pl1.y, i1 + 1, bv2, bi2);
            updf(pl1.z, i1 + 2, bv3, bi3); updf(pl1.w, i1 + 3, bv3, bi3);
        }
        // tail: 416 float4 (guarded)
        for (int w = start + NFULL * STRIDE + threadIdx.x; w < end; w += BLOCK) {
            f32x4 a = ntload(lg + w);
            int i0 = w << 2;
            updf(a.x, i0 + 0, bv0, bi0); updf(a.y, i0 + 1, bv0, bi0);
            updf(a.z, i0 + 2, bv1, bi1); updf(a.w, i0 + 3, bv1, bi1);
        }
    } else {
        // sampled rows: argmax( l*(invT*log2e) - log2(max(noise, 1e-10)) )
        int v = start + threadIdx.x;
        f32x4 pl0 = ntload(lg + v);
        f32x4 pl1 = ntload(lg + v + BLOCK);
        f32x4 pn0 = ntload(nz + v);
        f32x4 pn1 = ntload(nz + v + BLOCK);
        #pragma unroll 2
        for (int k = 1; k < NFULL; ++k) {
            const int vn = start + k * STRIDE + threadIdx.x;
            f32x4 cl0 = pl0, cl1 = pl1, cn0 = pn0, cn1 = pn1;
            pl0 = ntload(lg + vn);                 // prefetch next iter: 4 dwordx4 in flight
            pl1 = ntload(lg + vn + BLOCK);
            pn0 = ntload(nz + vn);
            pn1 = ntload(nz + vn + BLOCK);
            int i0 = v << 2, i1 = (v + BLOCK) << 2;
            updf(skey(cl0.x, cn0.x, invT2), i0 + 0, bv0, bi0);
            updf(skey(cl0.y, cn0.y, invT2), i0 + 1, bv0, bi0);
            updf(skey(cl0.z, cn0.z, invT2), i0 + 2, bv1, bi1);
            updf(skey(cl0.w, cn0.w, invT2), i0 + 3, bv1, bi1);
            updf(skey(cl1.x, cn1.x, invT2), i1 + 0, bv2, bi2);
            updf(skey(cl1.y, cn1.y, invT2), i1 + 1, bv2, bi2);
            updf(skey(cl1.z, cn1.z, invT2), i1 + 2, bv3, bi3);
            updf(skey(cl1.w, cn1.w, invT2), i1 + 3, bv3, bi3);
            v = vn;
        }
        { // drain
            int i0 = v << 2, i1 = (v + BLOCK) << 2;
            updf(skey(pl0.x, pn0.x, invT2), i0 + 0, bv0, bi0);
            updf(skey(pl0.y, pn0.y, invT2), i0 + 1, bv0, bi0);
            updf(skey(pl0.z, pn0.z, invT2), i0 + 2, bv1, bi1);
            updf(skey(pl0.w, pn0.w, invT2), i0 + 3, bv1, bi1);
            updf(skey(pl1.x, pn1.x, invT2), i1 + 0, bv2, bi2);
            updf(skey(pl1.y, pn1.y, invT2), i1 + 1, bv2, bi2);
            updf(skey(pl1.z, pn1.z, invT2), i1 + 2, bv3, bi3);
            updf(skey(pl1.w, pn1.w, invT2), i1 + 3, bv3, bi3);
        }
        // tail: 416 float4 (guarded)
        for (int w = start + NFULL * STRIDE + threadIdx.x; w < end; w += BLOCK) {
            f32x4 l = ntload(lg + w);
            f32x4 n = ntload(nz + w);
            int i0 = w << 2;
            updf(skey(l.x, n.x, invT2), i0 + 0, bv0, bi0);
            updf(skey(l.y, n.y, invT2), i0 + 1, bv0, bi0);
            updf(skey(l.z, n.z, invT2), i0 + 2, bv1, bi1);
            updf(skey(l.w, n.w, invT2), i0 + 3, bv1, bi1);
        }
    }

    // merge the 4 accumulators with full tie-break (cross-chain ties need index compare)
    mergeAcc(bv1, bi1, bv0, bi0);
    mergeAcc(bv2, bi2, bv0, bi0);
    mergeAcc(bv3, bi3, bv0, bi0);

    // packed-key wave (64-lane) max reduction
    unsigned long long key = packKey(bv0, bi0);
    #pragma unroll
    for (int off = 32; off > 0; off >>= 1) {
        unsigned long long o = __shfl_down(key, off, 64);
        key = (o > key) ? o : key;
    }

    // cross-wave reduction (4 waves)
    __shared__ unsigned long long sKey[BLOCK / 64];
    const int wave = threadIdx.x >> 6;
    const int lane = threadIdx.x & 63;
    if (lane == 0) sKey[wave] = key;
    __syncthreads();

    if (threadIdx.x == 0) {
        unsigned long long k = sKey[0];
        #pragma unroll
        for (int w = 1; w < BLOCK / 64; ++w)
            k = (sKey[w] > k) ? sKey[w] : k;
        partials[blockIdx.x] = k;   // [row * CHUNKS + chunk]
    }
}

__global__ void reduce_kernel(const unsigned long long* __restrict__ partials,
                              int* __restrict__ out)
{
    const int row = blockIdx.x * blockDim.x + threadIdx.x;
    if (row < B) {
        unsigned long long k = partials[(size_t)row * CHUNKS];
        #pragma unroll
        for (int c = 1; c < CHUNKS; ++c) {
            unsigned long long o = partials[(size_t)row * CHUNKS + c];
            k = (o > k) ? o : k;
        }
        out[row] = (int)(~(unsigned int)k);   // decode index from low 32 bits
    }
}

extern "C" void kernel_launch(void* const* d_in, const int* in_sizes, int n_in,
                              void* d_out, int out_size, void* d_ws, size_t ws_size,
                              hipStream_t stream) {
    const float* logits = (const float*)d_in[0];   // [B, V] f32
    const float* temps  = (const float*)d_in[1];   // [B]    f32
    const float* noise  = (const float*)d_in[2];   // [B, V] f32
    int* out = (int*)d_out;                        // [B] int32 (jax int64 -> int32, x64 off)

    unsigned long long* partials = (unsigned long long*)d_ws;  // B*CHUNKS*8 = 16 KB

    partial_kernel<<<B * CHUNKS, BLOCK, 0, stream>>>(logits, temps, noise, partials);
    reduce_kernel<<<1, B, 0, stream>>>(partials, out);
}